// Round 6
// baseline (390.324 us; speedup 1.0000x reference)
//
#include <hip/hip_runtime.h>
#include <hip/hip_bf16.h>

typedef __attribute__((ext_vector_type(8))) short short8;
typedef __attribute__((ext_vector_type(4))) float f32x4;

#define DM 1024
#define NH 16
#define HS 64
#define SEQL 2048

__device__ __forceinline__ short f2bf(float f) {
  unsigned u;
  __builtin_memcpy(&u, &f, 4);
  u = u + 0x7FFFu + ((u >> 16) & 1u);   // RNE
  return (short)(u >> 16);
}

// ---- weight pack: Wt[h][hs][dm] = bf16(W[h][dm][hs]) for Q/K/V (fp32 in) ----
__global__ __launch_bounds__(256) void pack_w_kernel(
    const float* __restrict__ Wq, const float* __restrict__ Wk, const float* __restrict__ Wv,
    short* __restrict__ WtQ, short* __restrict__ WtK, short* __restrict__ WtV) {
  const float* W = (blockIdx.y == 0) ? Wq : (blockIdx.y == 1) ? Wk : Wv;
  short* Wt      = (blockIdx.y == 0) ? WtQ : (blockIdx.y == 1) ? WtK : WtV;
  int idx = blockIdx.x * 256 + threadIdx.x;   // [h][dm][hs], hs fastest (coalesced read)
  int hs = idx & 63;
  int dm = (idx >> 6) & 1023;
  int h = idx >> 16;
  Wt[(h * 64 + hs) * 1024 + dm] = f2bf(W[idx]);
}

// ---------------- GEMM: C[m][n] = sum_k A[m][k]*Bt[n][k] + bias[n] ----------------
// AFP32/BFP32: operand is fp32 in global, converted to bf16 during LDS staging.
// mode 0: store bf16 to [b][h][s][64] (QKV);  mode 1: store FP32 row-major [m][1024]
struct GemmArgs {
  const void* A;       // [M x 1024] row-major
  const void* Bt;      // [1024 x 1024] row-major (n-major, k contiguous)
  const float* bias;   // [1024] fp32
  short* out;          // mode-0 destination (bf16)
  float* outf;         // mode-1 destination (fp32)
};

template <bool AFP32, bool BFP32>
__global__ __launch_bounds__(256) void gemm_bt_kernel(GemmArgs g0, GemmArgs g1, GemmArgs g2, int mode) {
  GemmArgs g = (blockIdx.z == 0) ? g0 : (blockIdx.z == 1) ? g1 : g2;
  const int K = 1024;
  const int m0 = blockIdx.x * 128;
  const int n0 = blockIdx.y * 128;
  const int tid = threadIdx.x;
  const int w = tid >> 6, l = tid & 63, lr = l & 15, lk = l >> 4;
  const int wr = w >> 1, wc = w & 1;

  __shared__ __align__(16) short As[128][40];   // +8 pad: stride 80B (16B-mult), 2-way banks (free)
  __shared__ __align__(16) short Bs[128][40];

  f32x4 acc[4][4];
#pragma unroll
  for (int i = 0; i < 4; ++i)
#pragma unroll
    for (int j = 0; j < 4; ++j) acc[i][j] = (f32x4){0.f, 0.f, 0.f, 0.f};

  for (int k0 = 0; k0 < K; k0 += 32) {
    __syncthreads();
#pragma unroll
    for (int i = 0; i < 2; ++i) {
      int q = tid * 2 + i;               // 512 8-elem chunks: 128 rows x 4 chunks
      int row = q >> 2, kc = (q & 3) * 8;
      short8 av, bv;
      if (AFP32) {
        const f32x4* ap = (const f32x4*)((const float*)g.A + (size_t)(m0 + row) * K + k0 + kc);
        f32x4 f0 = ap[0], f1 = ap[1];
#pragma unroll
        for (int j = 0; j < 4; ++j) { av[j] = f2bf(f0[j]); av[4 + j] = f2bf(f1[j]); }
      } else {
        av = *(const short8*)((const short*)g.A + (size_t)(m0 + row) * K + k0 + kc);
      }
      if (BFP32) {
        const f32x4* bp = (const f32x4*)((const float*)g.Bt + (size_t)(n0 + row) * K + k0 + kc);
        f32x4 f0 = bp[0], f1 = bp[1];
#pragma unroll
        for (int j = 0; j < 4; ++j) { bv[j] = f2bf(f0[j]); bv[4 + j] = f2bf(f1[j]); }
      } else {
        bv = *(const short8*)((const short*)g.Bt + (size_t)(n0 + row) * K + k0 + kc);
      }
      *(short8*)&As[row][kc] = av;
      *(short8*)&Bs[row][kc] = bv;
    }
    __syncthreads();
    short8 af[4], bfr[4];
#pragma unroll
    for (int t = 0; t < 4; ++t) {
      // A-frag: A[m=lr][k=lk*8+j]; B-frag: B[k=lk*8+j][n=lr] = Bt[n][k]
      af[t]  = *(const short8*)&As[wr * 64 + t * 16 + lr][lk * 8];
      bfr[t] = *(const short8*)&Bs[wc * 64 + t * 16 + lr][lk * 8];
    }
#pragma unroll
    for (int ti = 0; ti < 4; ++ti)
#pragma unroll
      for (int tj = 0; tj < 4; ++tj)
        acc[ti][tj] = __builtin_amdgcn_mfma_f32_16x16x32_bf16(af[ti], bfr[tj], acc[ti][tj], 0, 0, 0);
  }

#pragma unroll
  for (int ti = 0; ti < 4; ++ti)
#pragma unroll
    for (int tj = 0; tj < 4; ++tj) {
      int n = n0 + wc * 64 + tj * 16 + lr;
      float bia = g.bias[n];
#pragma unroll
      for (int r = 0; r < 4; ++r) {
        int m = m0 + wr * 64 + ti * 16 + lk * 4 + r;   // C: row=(l>>4)*4+r, col=l&15
        float v = acc[ti][tj][r] + bia;
        if (mode == 0) {
          // out[((b*16)+h)*2048*64 + s*64 + d], b=m>>11, s=m&2047, h=n>>6, d=n&63
          g.out[((m >> 11) * 16 + (n >> 6)) * (SEQL * HS) + (m & 2047) * HS + (n & 63)] = f2bf(v);
        } else {
          g.outf[(size_t)m * DM + n] = v;              // fp32 output
        }
      }
    }
}

// ---------------- flash attention: per (b,h), O = softmax(Q K^T / 8) V ----------------
// KV-tile = 64 rows -> LDS = 39936 B. All inputs bf16 (our ws buffers).
__global__ __launch_bounds__(256) void attn_kernel(const short* __restrict__ Qg, const short* __restrict__ Kg,
                                                   const short* __restrict__ Vg, short* __restrict__ Og) {
  const int qt = blockIdx.x;   // 16 q-tiles of 128 rows
  const int bh = blockIdx.y;   // 32 (b,h)
  const short* Qp = Qg + bh * SEQL * HS;
  const short* Kp = Kg + bh * SEQL * HS;
  const short* Vp = Vg + bh * SEQL * HS;
  const int tid = threadIdx.x, w = tid >> 6, l = tid & 63, lr = l & 15, lk = l >> 4;
  const int q0 = qt * 128;

  __shared__ __align__(16) short Ks[64][72];       // K tile row-major (+8 pad)
  __shared__ __align__(16) short Vt[64][80];       // V transposed: Vt[d][s] (+16 pad)
  __shared__ __align__(16) short Ps[4][32][80];    // per-wave P scratch (C-layout -> A-layout)

  short8 qf[2][2];
#pragma unroll
  for (int ti = 0; ti < 2; ++ti)
#pragma unroll
    for (int kk = 0; kk < 2; ++kk)
      qf[ti][kk] = *(const short8*)&Qp[(q0 + w * 32 + ti * 16 + lr) * HS + kk * 32 + lk * 8];

  float mrow[2][4], lrow[2][4];
  f32x4 accO[2][4];
#pragma unroll
  for (int ti = 0; ti < 2; ++ti)
#pragma unroll
    for (int r = 0; r < 4; ++r) { mrow[ti][r] = -1e30f; lrow[ti][r] = 0.f; }
#pragma unroll
  for (int ti = 0; ti < 2; ++ti)
#pragma unroll
    for (int tjO = 0; tjO < 4; ++tjO) accO[ti][tjO] = (f32x4){0.f, 0.f, 0.f, 0.f};

  const float scale = 0.125f;  // 1/sqrt(64)

  for (int kv = 0; kv < 32; ++kv) {
    __syncthreads();
#pragma unroll
    for (int i = 0; i < 2; ++i) {
      int q = tid + i * 256;            // 512 chunks: 64 rows x 8 chunks of 8 bf16
      int row = q >> 3, col = (q & 7) * 8;
      *(short8*)&Ks[row][col] = *(const short8*)&Kp[(kv * 64 + row) * HS + col];
      short8 tv = *(const short8*)&Vp[(kv * 64 + row) * HS + col];
#pragma unroll
      for (int j = 0; j < 8; ++j) Vt[col + j][row] = tv[j];
    }
    __syncthreads();

    // S = Q K^T : M=32 (wave rows), N=64 (KV tile), Kdim=64
    f32x4 accS[2][4];
#pragma unroll
    for (int tj = 0; tj < 4; ++tj) {
      short8 b0 = *(const short8*)&Ks[tj * 16 + lr][lk * 8];
      short8 b1 = *(const short8*)&Ks[tj * 16 + lr][32 + lk * 8];
#pragma unroll
      for (int ti = 0; ti < 2; ++ti) {
        f32x4 z = (f32x4){0.f, 0.f, 0.f, 0.f};
        z = __builtin_amdgcn_mfma_f32_16x16x32_bf16(qf[ti][0], b0, z, 0, 0, 0);
        accS[ti][tj] = __builtin_amdgcn_mfma_f32_16x16x32_bf16(qf[ti][1], b1, z, 0, 0, 0);
      }
    }

    // online softmax; row = ti*16 + lk*4 + r; 16 lanes (lr) hold the row's columns
#pragma unroll
    for (int ti = 0; ti < 2; ++ti)
#pragma unroll
      for (int r = 0; r < 4; ++r) {
        float mx = accS[ti][0][r];
#pragma unroll
        for (int tj = 1; tj < 4; ++tj) mx = fmaxf(mx, accS[ti][tj][r]);
        mx = fmaxf(mx, __shfl_xor(mx, 1));
        mx = fmaxf(mx, __shfl_xor(mx, 2));
        mx = fmaxf(mx, __shfl_xor(mx, 4));
        mx = fmaxf(mx, __shfl_xor(mx, 8));
        mx *= scale;
        float mn = fmaxf(mrow[ti][r], mx);
        float alpha = __expf(fminf(mrow[ti][r] - mn, 0.f));
        float ps = 0.f;
#pragma unroll
        for (int tj = 0; tj < 4; ++tj) {
          float p = __expf(fminf(accS[ti][tj][r] * scale - mn, 0.f));
          accS[ti][tj][r] = p;
          ps += p;
        }
        ps += __shfl_xor(ps, 1);
        ps += __shfl_xor(ps, 2);
        ps += __shfl_xor(ps, 4);
        ps += __shfl_xor(ps, 8);
        lrow[ti][r] = lrow[ti][r] * alpha + ps;
        mrow[ti][r] = mn;
#pragma unroll
        for (int tjO = 0; tjO < 4; ++tjO) accO[ti][tjO][r] *= alpha;
      }

    // P: C-layout -> LDS (wave-private, same-wave DS ordering)
#pragma unroll
    for (int ti = 0; ti < 2; ++ti)
#pragma unroll
      for (int tj = 0; tj < 4; ++tj)
#pragma unroll
        for (int r = 0; r < 4; ++r)
          Ps[w][ti * 16 + lk * 4 + r][tj * 16 + lr] = f2bf(accS[ti][tj][r]);

    // O += P V : M=32, N=64, Kdim=64
#pragma unroll
    for (int kk = 0; kk < 2; ++kk) {
      short8 vf[4];
#pragma unroll
      for (int tjO = 0; tjO < 4; ++tjO) vf[tjO] = *(const short8*)&Vt[tjO * 16 + lr][kk * 32 + lk * 8];
#pragma unroll
      for (int ti = 0; ti < 2; ++ti) {
        short8 pf = *(const short8*)&Ps[w][ti * 16 + lr][kk * 32 + lk * 8];
#pragma unroll
        for (int tjO = 0; tjO < 4; ++tjO)
          accO[ti][tjO] = __builtin_amdgcn_mfma_f32_16x16x32_bf16(pf, vf[tjO], accO[ti][tjO], 0, 0, 0);
      }
    }
  }

  // epilogue: out[b][s][h*64+d] (bf16 intermediate buffer)
  const int b = bh >> 4, h = bh & 15;
#pragma unroll
  for (int ti = 0; ti < 2; ++ti)
#pragma unroll
    for (int r = 0; r < 4; ++r) {
      int s = q0 + w * 32 + ti * 16 + lk * 4 + r;
      float inv = 1.f / fmaxf(lrow[ti][r], 1e-30f);
#pragma unroll
      for (int tjO = 0; tjO < 4; ++tjO) {
        int d = tjO * 16 + lr;
        Og[(b * SEQL + s) * DM + h * HS + d] = f2bf(accO[ti][tjO][r] * inv);
      }
    }
}

extern "C" void kernel_launch(void* const* d_in, const int* in_sizes, int n_in,
                              void* d_out, int out_size, void* d_ws, size_t ws_size,
                              hipStream_t stream) {
  const float* query  = (const float*)d_in[0];
  const float* key_in = (const float*)d_in[1];
  const float* value  = (const float*)d_in[2];
  const float* Wq = (const float*)d_in[3];
  const float* Wk = (const float*)d_in[4];
  const float* Wv = (const float*)d_in[5];
  const float* bq = (const float*)d_in[6];
  const float* bk = (const float*)d_in[7];
  const float* bv = (const float*)d_in[8];
  const float* Wo = (const float*)d_in[9];
  const float* bo = (const float*)d_in[10];
  float* out = (float*)d_out;          // FP32 output

  // ws layout (shorts), TOTAL = 16M shorts = 32 MB:
  //   [0,4M)   Qb   [b][h][s][64]
  //   [4M,8M)  Kb
  //   [8M,12M) Vb
  //   [12M,16M) X: WtQ/WtK/WtV (3x1M, live until QKV GEMM done) then At (4M, from attn on)
  short* ws  = (short*)d_ws;
  short* Qb  = ws;
  short* Kb  = Qb + (4 << 20);
  short* Vb  = Kb + (4 << 20);
  short* X   = Vb + (4 << 20);
  short* WtQ = X;
  short* WtK = WtQ + (1 << 20);
  short* WtV = WtK + (1 << 20);
  short* At  = X;                     // aliases Wt trio (disjoint lifetimes)

  pack_w_kernel<<<dim3(4096, 3), 256, 0, stream>>>(Wq, Wk, Wv, WtQ, WtK, WtV);

  GemmArgs gq{query, WtQ, bq, Qb, nullptr}, gk{key_in, WtK, bk, Kb, nullptr},
           gv{value, WtV, bv, Vb, nullptr};
  gemm_bt_kernel<true, false><<<dim3(32, 8, 3), 256, 0, stream>>>(gq, gk, gv, 0);

  attn_kernel<<<dim3(16, 32), 256, 0, stream>>>(Qb, Kb, Vb, At);

  GemmArgs go{At, Wo, bo, nullptr, out};
  gemm_bt_kernel<false, true><<<dim3(32, 8, 1), 256, 0, stream>>>(go, go, go, 1);
}

// Round 7
// 343.162 us; speedup vs baseline: 1.1374x; 1.1374x over previous
//
#include <hip/hip_runtime.h>
#include <hip/hip_bf16.h>

typedef __attribute__((ext_vector_type(8))) short short8;
typedef __attribute__((ext_vector_type(4))) float f32x4;

#define DM 1024
#define NH 16
#define HS 64
#define SEQL 2048

__device__ __forceinline__ float bf2f(short s) {
  unsigned u = ((unsigned)(unsigned short)s) << 16;
  float f;
  __builtin_memcpy(&f, &u, 4);
  return f;
}
__device__ __forceinline__ short f2bf(float f) {
  unsigned u;
  __builtin_memcpy(&u, &f, 4);
  u = u + 0x7FFFu + ((u >> 16) & 1u);   // RNE
  return (short)(u >> 16);
}

// ---- weight pack: Wt[h][hs][dm] = bf16(W[h][dm][hs]) for Q/K/V (fp32 in) ----
__global__ __launch_bounds__(256) void pack_w_kernel(
    const float* __restrict__ Wq, const float* __restrict__ Wk, const float* __restrict__ Wv,
    short* __restrict__ WtQ, short* __restrict__ WtK, short* __restrict__ WtV) {
  const float* W = (blockIdx.y == 0) ? Wq : (blockIdx.y == 1) ? Wk : Wv;
  short* Wt      = (blockIdx.y == 0) ? WtQ : (blockIdx.y == 1) ? WtK : WtV;
  int idx = blockIdx.x * 256 + threadIdx.x;   // [h][dm][hs], hs fastest (coalesced read)
  int hs = idx & 63;
  int dm = (idx >> 6) & 1023;
  int h = idx >> 16;
  Wt[(h * 64 + hs) * 1024 + dm] = f2bf(W[idx]);
}

// ---------------- GEMM: C[m][n] = sum_k A[m][k]*Bt[n][k] + bias[n] ----------------
// AFP32/BFP32: operand is fp32 in global, converted to bf16 during LDS staging.
// mode 0: bf16 [b][h][s][64];  mode 2: bf16 [b][h][d][s] (transposed, for V);
// mode 1: fp32 row-major [m][1024]
struct GemmArgs {
  const void* A;       // [M x 1024] row-major
  const void* Bt;      // [1024 x 1024] row-major (n-major, k contiguous)
  const float* bias;   // [1024] fp32
  short* out;          // bf16 destination (mode 0/2)
  float* outf;         // fp32 destination (mode 1)
  int mode;
};

template <bool AFP32, bool BFP32>
__global__ __launch_bounds__(256) void gemm_bt_kernel(GemmArgs g0, GemmArgs g1, GemmArgs g2) {
  GemmArgs g = (blockIdx.z == 0) ? g0 : (blockIdx.z == 1) ? g1 : g2;
  const int K = 1024;
  const int m0 = blockIdx.x * 128;
  const int n0 = blockIdx.y * 128;
  const int tid = threadIdx.x;
  const int w = tid >> 6, l = tid & 63, lr = l & 15, lk = l >> 4;
  const int wr = w >> 1, wc = w & 1;

  __shared__ __align__(16) short As[128][40];   // +8 pad: stride 80B (16B-mult), 2-way banks (free)
  __shared__ __align__(16) short Bs[128][40];

  f32x4 acc[4][4];
#pragma unroll
  for (int i = 0; i < 4; ++i)
#pragma unroll
    for (int j = 0; j < 4; ++j) acc[i][j] = (f32x4){0.f, 0.f, 0.f, 0.f};

  for (int k0 = 0; k0 < K; k0 += 32) {
    __syncthreads();
#pragma unroll
    for (int i = 0; i < 2; ++i) {
      int q = tid * 2 + i;               // 512 8-elem chunks: 128 rows x 4 chunks
      int row = q >> 2, kc = (q & 3) * 8;
      short8 av, bv;
      if (AFP32) {
        const f32x4* ap = (const f32x4*)((const float*)g.A + (size_t)(m0 + row) * K + k0 + kc);
        f32x4 f0 = ap[0], f1 = ap[1];
#pragma unroll
        for (int j = 0; j < 4; ++j) { av[j] = f2bf(f0[j]); av[4 + j] = f2bf(f1[j]); }
      } else {
        av = *(const short8*)((const short*)g.A + (size_t)(m0 + row) * K + k0 + kc);
      }
      if (BFP32) {
        const f32x4* bp = (const f32x4*)((const float*)g.Bt + (size_t)(n0 + row) * K + k0 + kc);
        f32x4 f0 = bp[0], f1 = bp[1];
#pragma unroll
        for (int j = 0; j < 4; ++j) { bv[j] = f2bf(f0[j]); bv[4 + j] = f2bf(f1[j]); }
      } else {
        bv = *(const short8*)((const short*)g.Bt + (size_t)(n0 + row) * K + k0 + kc);
      }
      *(short8*)&As[row][kc] = av;
      *(short8*)&Bs[row][kc] = bv;
    }
    __syncthreads();
    short8 af[4], bfr[4];
#pragma unroll
    for (int t = 0; t < 4; ++t) {
      // A-frag: A[m=lr][k=lk*8+j]; B-frag: B[k=lk*8+j][n=lr] = Bt[n][k]
      af[t]  = *(const short8*)&As[wr * 64 + t * 16 + lr][lk * 8];
      bfr[t] = *(const short8*)&Bs[wc * 64 + t * 16 + lr][lk * 8];
    }
#pragma unroll
    for (int ti = 0; ti < 4; ++ti)
#pragma unroll
      for (int tj = 0; tj < 4; ++tj)
        acc[ti][tj] = __builtin_amdgcn_mfma_f32_16x16x32_bf16(af[ti], bfr[tj], acc[ti][tj], 0, 0, 0);
  }

#pragma unroll
  for (int ti = 0; ti < 4; ++ti)
#pragma unroll
    for (int tj = 0; tj < 4; ++tj) {
      int n = n0 + wc * 64 + tj * 16 + lr;
      float bia = g.bias[n];
#pragma unroll
      for (int r = 0; r < 4; ++r) {
        int m = m0 + wr * 64 + ti * 16 + lk * 4 + r;   // C: row=(l>>4)*4+r, col=l&15
        float v = acc[ti][tj][r] + bia;
        if (g.mode == 0) {
          // [b][h][s][d]: b=m>>11, s=m&2047, h=n>>6, d=n&63
          g.out[((m >> 11) * 16 + (n >> 6)) * (SEQL * HS) + (m & 2047) * HS + (n & 63)] = f2bf(v);
        } else if (g.mode == 2) {
          // [b][h][d][s] (transposed V)
          g.out[((m >> 11) * 16 + (n >> 6)) * (SEQL * HS) + (n & 63) * SEQL + (m & 2047)] = f2bf(v);
        } else {
          g.outf[(size_t)m * DM + n] = v;              // fp32 output
        }
      }
    }
}

// ---------------- flash attention: per (b,h), O = softmax(Q K^T / 8) V ----------------
// KV-tile = 128. V pre-transposed in global ([bh][d][s]). LDS = 54.3 KB.
__global__ __launch_bounds__(256) void attn_kernel(const short* __restrict__ Qg, const short* __restrict__ Kg,
                                                   const short* __restrict__ Vtg, short* __restrict__ Og) {
  const int qt = blockIdx.x;   // 16 q-tiles of 128 rows
  const int bh = blockIdx.y;   // 32 (b,h)
  const short* Qp = Qg + bh * SEQL * HS;
  const short* Kp = Kg + bh * SEQL * HS;
  const short* Vp = Vtg + bh * HS * SEQL;   // [d][s]
  const int tid = threadIdx.x, w = tid >> 6, l = tid & 63, lr = l & 15, lk = l >> 4;
  const int q0 = qt * 128;

  __shared__ __align__(16) short Ks[128][72];      // K tile row-major (+8 pad)
  __shared__ __align__(16) short Vt[64][136];      // V^T tile: [d][s] (+8 pad)
  __shared__ __align__(16) short Ps[4][32][72];    // per-wave P scratch (reused for 2 chunks)

  // Q fragments in registers, pre-scaled by 1/sqrt(64)=0.125 (exact in bf16)
  short8 qf[2][2];
#pragma unroll
  for (int ti = 0; ti < 2; ++ti)
#pragma unroll
    for (int kk = 0; kk < 2; ++kk) {
      short8 qr = *(const short8*)&Qp[(q0 + w * 32 + ti * 16 + lr) * HS + kk * 32 + lk * 8];
#pragma unroll
      for (int j = 0; j < 8; ++j) qf[ti][kk][j] = f2bf(bf2f(qr[j]) * 0.125f);
    }

  float mrow[2][4], lrow[2][4];
  f32x4 accO[2][4];
#pragma unroll
  for (int ti = 0; ti < 2; ++ti)
#pragma unroll
    for (int r = 0; r < 4; ++r) { mrow[ti][r] = -1e30f; lrow[ti][r] = 0.f; }
#pragma unroll
  for (int ti = 0; ti < 2; ++ti)
#pragma unroll
    for (int tjO = 0; tjO < 4; ++tjO) accO[ti][tjO] = (f32x4){0.f, 0.f, 0.f, 0.f};

  for (int kv = 0; kv < 16; ++kv) {
    __syncthreads();
    // stage K tile 128x64 (coalesced, b128 LDS writes)
#pragma unroll
    for (int i = 0; i < 4; ++i) {
      int q = tid + i * 256;            // 1024 chunks: 128 rows x 8 chunks
      int row = q >> 3, col = (q & 7) * 8;
      *(short8*)&Ks[row][col] = *(const short8*)&Kp[(kv * 128 + row) * HS + col];
    }
    // stage V^T tile 64x128 (coalesced rows of pre-transposed V, b128 LDS writes)
#pragma unroll
    for (int i = 0; i < 4; ++i) {
      int q = tid + i * 256;            // 1024 chunks: 64 d-rows x 16 chunks
      int d = q >> 4, sc = (q & 15) * 8;
      *(short8*)&Vt[d][sc] = *(const short8*)&Vp[d * SEQL + kv * 128 + sc];
    }
    __syncthreads();

    // S = Qs K^T : M=32 (wave rows), N=128, Kdim=64 (already scaled via Q)
    f32x4 accS[2][8];
#pragma unroll
    for (int tj = 0; tj < 8; ++tj) {
      short8 b0 = *(const short8*)&Ks[tj * 16 + lr][lk * 8];
      short8 b1 = *(const short8*)&Ks[tj * 16 + lr][32 + lk * 8];
#pragma unroll
      for (int ti = 0; ti < 2; ++ti) {
        f32x4 z = (f32x4){0.f, 0.f, 0.f, 0.f};
        z = __builtin_amdgcn_mfma_f32_16x16x32_bf16(qf[ti][0], b0, z, 0, 0, 0);
        accS[ti][tj] = __builtin_amdgcn_mfma_f32_16x16x32_bf16(qf[ti][1], b1, z, 0, 0, 0);
      }
    }

    // online softmax; row = ti*16 + lk*4 + r; 16 lanes (lr) hold the row's columns
#pragma unroll
    for (int ti = 0; ti < 2; ++ti)
#pragma unroll
      for (int r = 0; r < 4; ++r) {
        float mx = accS[ti][0][r];
#pragma unroll
        for (int tj = 1; tj < 8; ++tj) mx = fmaxf(mx, accS[ti][tj][r]);
        mx = fmaxf(mx, __shfl_xor(mx, 1));
        mx = fmaxf(mx, __shfl_xor(mx, 2));
        mx = fmaxf(mx, __shfl_xor(mx, 4));
        mx = fmaxf(mx, __shfl_xor(mx, 8));
        float mn = fmaxf(mrow[ti][r], mx);
        float alpha = __expf(mrow[ti][r] - mn);
        float ps = 0.f;
#pragma unroll
        for (int tj = 0; tj < 8; ++tj) {
          float p = __expf(accS[ti][tj][r] - mn);   // arg <= 0 by construction
          accS[ti][tj][r] = p;
          ps += p;
        }
        ps += __shfl_xor(ps, 1);
        ps += __shfl_xor(ps, 2);
        ps += __shfl_xor(ps, 4);
        ps += __shfl_xor(ps, 8);
        lrow[ti][r] = lrow[ti][r] * alpha + ps;
        mrow[ti][r] = mn;
#pragma unroll
        for (int tjO = 0; tjO < 4; ++tjO) accO[ti][tjO][r] *= alpha;
      }

    // O += P V in two 64-col chunks (Ps reused; wave-private, DS pipe is in-order per wave)
#pragma unroll
    for (int c = 0; c < 2; ++c) {
#pragma unroll
      for (int ti = 0; ti < 2; ++ti)
#pragma unroll
        for (int tjq = 0; tjq < 4; ++tjq)
#pragma unroll
          for (int r = 0; r < 4; ++r)
            Ps[w][ti * 16 + lk * 4 + r][tjq * 16 + lr] = f2bf(accS[ti][c * 4 + tjq][r]);
#pragma unroll
      for (int kk = 0; kk < 2; ++kk) {
        short8 vf[4];
#pragma unroll
        for (int tjO = 0; tjO < 4; ++tjO)
          vf[tjO] = *(const short8*)&Vt[tjO * 16 + lr][c * 64 + kk * 32 + lk * 8];
#pragma unroll
        for (int ti = 0; ti < 2; ++ti) {
          short8 pf = *(const short8*)&Ps[w][ti * 16 + lr][kk * 32 + lk * 8];
#pragma unroll
          for (int tjO = 0; tjO < 4; ++tjO)
            accO[ti][tjO] = __builtin_amdgcn_mfma_f32_16x16x32_bf16(pf, vf[tjO], accO[ti][tjO], 0, 0, 0);
        }
      }
    }
  }

  // epilogue: out[b][s][h*64+d] (bf16 intermediate buffer)
  const int b = bh >> 4, h = bh & 15;
#pragma unroll
  for (int ti = 0; ti < 2; ++ti)
#pragma unroll
    for (int r = 0; r < 4; ++r) {
      int s = q0 + w * 32 + ti * 16 + lk * 4 + r;
      float inv = 1.f / fmaxf(lrow[ti][r], 1e-30f);
#pragma unroll
      for (int tjO = 0; tjO < 4; ++tjO) {
        int d = tjO * 16 + lr;
        Og[(b * SEQL + s) * DM + h * HS + d] = f2bf(accO[ti][tjO][r] * inv);
      }
    }
}

extern "C" void kernel_launch(void* const* d_in, const int* in_sizes, int n_in,
                              void* d_out, int out_size, void* d_ws, size_t ws_size,
                              hipStream_t stream) {
  const float* query  = (const float*)d_in[0];
  const float* key_in = (const float*)d_in[1];
  const float* value  = (const float*)d_in[2];
  const float* Wq = (const float*)d_in[3];
  const float* Wk = (const float*)d_in[4];
  const float* Wv = (const float*)d_in[5];
  const float* bq = (const float*)d_in[6];
  const float* bk = (const float*)d_in[7];
  const float* bv = (const float*)d_in[8];
  const float* Wo = (const float*)d_in[9];
  const float* bo = (const float*)d_in[10];
  float* out = (float*)d_out;          // FP32 output

  // ws layout (shorts), TOTAL = 16M shorts = 32 MB:
  //   [0,4M)   Qb   [b][h][s][64]
  //   [4M,8M)  Kb   [b][h][s][64]
  //   [8M,12M) Vbt  [b][h][64][s]  (pre-transposed V)
  //   [12M,16M) X: WtQ/WtK/WtV (3x1M, live until QKV GEMM done) then At (4M, from attn on)
  short* ws  = (short*)d_ws;
  short* Qb  = ws;
  short* Kb  = Qb + (4 << 20);
  short* Vbt = Kb + (4 << 20);
  short* X   = Vbt + (4 << 20);
  short* WtQ = X;
  short* WtK = WtQ + (1 << 20);
  short* WtV = WtK + (1 << 20);
  short* At  = X;                     // aliases Wt trio (disjoint lifetimes)

  pack_w_kernel<<<dim3(4096, 3), 256, 0, stream>>>(Wq, Wk, Wv, WtQ, WtK, WtV);

  GemmArgs gq{query, WtQ, bq, Qb, nullptr, 0}, gk{key_in, WtK, bk, Kb, nullptr, 0},
           gv{value, WtV, bv, Vbt, nullptr, 2};
  gemm_bt_kernel<true, false><<<dim3(32, 8, 3), 256, 0, stream>>>(gq, gk, gv);

  attn_kernel<<<dim3(16, 32), 256, 0, stream>>>(Qb, Kb, Vbt, At);

  GemmArgs go{At, Wo, bo, nullptr, out, 1};
  gemm_bt_kernel<false, true><<<dim3(32, 8, 1), 256, 0, stream>>>(go, go, go);
}

// Round 10
// 321.480 us; speedup vs baseline: 1.2141x; 1.0674x over previous
//
#include <hip/hip_runtime.h>
#include <hip/hip_bf16.h>

typedef __attribute__((ext_vector_type(8))) short short8;
typedef __attribute__((ext_vector_type(4))) short bf16x4;
typedef __attribute__((ext_vector_type(4))) float f32x4;

#define DM 1024
#define NH 16
#define HS 64
#define SEQL 2048

__device__ __forceinline__ float bf2f(short s) {
  unsigned u = ((unsigned)(unsigned short)s) << 16;
  float f;
  __builtin_memcpy(&f, &u, 4);
  return f;
}
__device__ __forceinline__ short f2bf(float f) {
  unsigned u;
  __builtin_memcpy(&u, &f, 4);
  u = u + 0x7FFFu + ((u >> 16) & 1u);   // RNE
  return (short)(u >> 16);
}

// ---- weight pack (LDS-tiled transpose): Wt[h][hs][dm] = bf16(W[h][dm][hs]) ----
__global__ __launch_bounds__(256) void pack_w_kernel(
    const float* __restrict__ Wq, const float* __restrict__ Wk, const float* __restrict__ Wv,
    short* __restrict__ WtQ, short* __restrict__ WtK, short* __restrict__ WtV) {
  const float* W = (blockIdx.z == 0) ? Wq : (blockIdx.z == 1) ? Wk : Wv;
  short* Wt      = (blockIdx.z == 0) ? WtQ : (blockIdx.z == 1) ? WtK : WtV;
  __shared__ short Ts[64][73];                 // [dm-within][hs], odd pad
  const int h = blockIdx.y, dm0 = blockIdx.x * 64;
  const int tid = threadIdx.x;
#pragma unroll
  for (int p = 0; p < 4; ++p) {                // read 64dm x 64hs as float4 (1024 chunks)
    int idx = p * 256 + tid;
    int i = idx >> 4, hsq = (idx & 15) * 4;    // coalesced float4 reads, hs fastest
    f32x4 v = *(const f32x4*)&W[((h << 10) + dm0 + i) * 64 + hsq];
#pragma unroll
    for (int j = 0; j < 4; ++j) Ts[i][hsq + j] = f2bf(v[j]);
  }
  __syncthreads();
  {                                            // write: 64 hs x 4 dm-quads = exactly 256 items
    int hs = tid >> 2, dmq = (tid & 3) * 16;
    short8 o0, o1;
#pragma unroll
    for (int j = 0; j < 8; ++j) { o0[j] = Ts[dmq + j][hs]; o1[j] = Ts[dmq + 8 + j][hs]; }
    short* dst = &Wt[((h * 64 + hs) << 10) + dm0 + dmq];
    *(short8*)dst = o0;
    *(short8*)(dst + 8) = o1;
  }
}

// ---------------- GEMM: C[m][n] = sum_k A[m][k]*Bt[n][k] + bias[n] ----------------
// AFP32/BFP32: operand is fp32 in global, converted to bf16 during LDS staging.
// mode 0: bf16 [b][h][s][64];  mode 2: bf16 [b][h][d][s] (transposed, for V);
// mode 1: fp32 row-major [m][1024]
struct GemmArgs {
  const void* A;
  const void* Bt;
  const float* bias;
  short* out;
  float* outf;
  int mode;
};

template <bool AFP32, bool BFP32>
__global__ __launch_bounds__(256) void gemm_bt_kernel(GemmArgs g0, GemmArgs g1, GemmArgs g2) {
  GemmArgs g = (blockIdx.z == 0) ? g0 : (blockIdx.z == 1) ? g1 : g2;
  const int K = 1024;
  const int m0 = blockIdx.x * 128;
  const int n0 = blockIdx.y * 128;
  const int tid = threadIdx.x;
  const int w = tid >> 6, l = tid & 63, lr = l & 15, lk = l >> 4;
  const int wr = w >> 1, wc = w & 1;

  __shared__ __align__(16) short As[128][40];
  __shared__ __align__(16) short Bs[128][40];

  f32x4 acc[4][4];
#pragma unroll
  for (int i = 0; i < 4; ++i)
#pragma unroll
    for (int j = 0; j < 4; ++j) acc[i][j] = (f32x4){0.f, 0.f, 0.f, 0.f};

  for (int k0 = 0; k0 < K; k0 += 32) {
    __syncthreads();
#pragma unroll
    for (int i = 0; i < 2; ++i) {
      int q = tid * 2 + i;
      int row = q >> 2, kc = (q & 3) * 8;
      short8 av, bv;
      if (AFP32) {
        const f32x4* ap = (const f32x4*)((const float*)g.A + (size_t)(m0 + row) * K + k0 + kc);
        f32x4 f0 = ap[0], f1 = ap[1];
#pragma unroll
        for (int j = 0; j < 4; ++j) { av[j] = f2bf(f0[j]); av[4 + j] = f2bf(f1[j]); }
      } else {
        av = *(const short8*)((const short*)g.A + (size_t)(m0 + row) * K + k0 + kc);
      }
      if (BFP32) {
        const f32x4* bp = (const f32x4*)((const float*)g.Bt + (size_t)(n0 + row) * K + k0 + kc);
        f32x4 f0 = bp[0], f1 = bp[1];
#pragma unroll
        for (int j = 0; j < 4; ++j) { bv[j] = f2bf(f0[j]); bv[4 + j] = f2bf(f1[j]); }
      } else {
        bv = *(const short8*)((const short*)g.Bt + (size_t)(n0 + row) * K + k0 + kc);
      }
      *(short8*)&As[row][kc] = av;
      *(short8*)&Bs[row][kc] = bv;
    }
    __syncthreads();
    short8 af[4], bfr[4];
#pragma unroll
    for (int t = 0; t < 4; ++t) {
      af[t]  = *(const short8*)&As[wr * 64 + t * 16 + lr][lk * 8];
      bfr[t] = *(const short8*)&Bs[wc * 64 + t * 16 + lr][lk * 8];
    }
#pragma unroll
    for (int ti = 0; ti < 4; ++ti)
#pragma unroll
      for (int tj = 0; tj < 4; ++tj)
        acc[ti][tj] = __builtin_amdgcn_mfma_f32_16x16x32_bf16(af[ti], bfr[tj], acc[ti][tj], 0, 0, 0);
  }

#pragma unroll
  for (int ti = 0; ti < 4; ++ti)
#pragma unroll
    for (int tj = 0; tj < 4; ++tj) {
      int n = n0 + wc * 64 + tj * 16 + lr;
      float bia = g.bias[n];
      int mb = m0 + wr * 64 + ti * 16 + lk * 4;        // C rows: mb..mb+3
      if (g.mode == 2) {
        bf16x4 o;
#pragma unroll
        for (int r = 0; r < 4; ++r) o[r] = f2bf(acc[ti][tj][r] + bia);
        // [b][h][d][s]: 4 consecutive s -> one 8B store
        *(bf16x4*)&g.out[((mb >> 11) * 16 + (n >> 6)) * (SEQL * HS) + (n & 63) * SEQL + (mb & 2047)] = o;
      } else {
#pragma unroll
        for (int r = 0; r < 4; ++r) {
          int m = mb + r;
          float v = acc[ti][tj][r] + bia;
          if (g.mode == 0) {
            g.out[((m >> 11) * 16 + (n >> 6)) * (SEQL * HS) + (m & 2047) * HS + (n & 63)] = f2bf(v);
          } else {
            g.outf[(size_t)m * DM + n] = v;
          }
        }
      }
    }
}

// ---------------- flash attention (S^T form): per (b,h), O = softmax(Q K^T / 8) V ----------------
// S^T = K Q^T via x32 MFMA (operand swap); P^T C-layout == B-frag layout of 16x16x16 MFMA,
// so PV needs no LDS round-trip and no shuffles. O accumulated transposed (O^T = V^T P^T).
// q-tile 64 (wave owns 16 q), KV-tile 128. LDS = 35.8 KB -> 4 blocks/CU.
__global__ __launch_bounds__(256, 4) void attn_kernel(const short* __restrict__ Qg, const short* __restrict__ Kg,
                                                      const short* __restrict__ Vtg, short* __restrict__ Og) {
  const int qt = blockIdx.x;   // 32 q-tiles of 64 rows
  const int bh = blockIdx.y;   // 32 (b,h)
  const short* Qp = Qg + bh * SEQL * HS;
  const short* Kp = Kg + bh * SEQL * HS;
  const short* Vp = Vtg + bh * HS * SEQL;   // [d][s]
  const int tid = threadIdx.x, w = tid >> 6, l = tid & 63, lr = l & 15, lk = l >> 4;
  const int qw = qt * 64 + w * 16;          // wave's q base (16 rows)

  __shared__ __align__(16) short Ks[128][72];      // K tile [kv][d]
  __shared__ __align__(16) short Vt[64][136];      // V^T tile [d][kv]

  // Q fragments (B-operand of S^T MFMA), pre-scaled by 1/8 (exact)
  short8 qf[2];
#pragma unroll
  for (int kk = 0; kk < 2; ++kk) {
    short8 qr = *(const short8*)&Qp[(qw + lr) * HS + kk * 32 + lk * 8];
#pragma unroll
    for (int j = 0; j < 8; ++j) qf[kk][j] = f2bf(bf2f(qr[j]) * 0.125f);
  }

  float mrow = -1e30f, lrow = 0.f;
  f32x4 accO[4];   // O^T tiles: row d = tjd*16 + lk*4 + r, col q = lr
#pragma unroll
  for (int t = 0; t < 4; ++t) accO[t] = (f32x4){0.f, 0.f, 0.f, 0.f};

  for (int kv = 0; kv < 16; ++kv) {
    __syncthreads();
#pragma unroll
    for (int i = 0; i < 4; ++i) {            // K tile: 128x64, coalesced b128
      int q = tid + i * 256;
      int row = q >> 3, col = (q & 7) * 8;
      *(short8*)&Ks[row][col] = *(const short8*)&Kp[(kv * 128 + row) * HS + col];
    }
#pragma unroll
    for (int i = 0; i < 4; ++i) {            // V^T tile: 64x128, coalesced b128
      int q = tid + i * 256;
      int d = q >> 4, sc = (q & 15) * 8;
      *(short8*)&Vt[d][sc] = *(const short8*)&Vp[d * SEQL + kv * 128 + sc];
    }
    __syncthreads();

    // S^T = K Qs^T : per wave M=128 kv (8 tiles), N=16 q
    f32x4 accS[8];
#pragma unroll
    for (int tj = 0; tj < 8; ++tj) {
      short8 a0 = *(const short8*)&Ks[tj * 16 + lr][lk * 8];
      short8 a1 = *(const short8*)&Ks[tj * 16 + lr][32 + lk * 8];
      f32x4 z = (f32x4){0.f, 0.f, 0.f, 0.f};
      z = __builtin_amdgcn_mfma_f32_16x16x32_bf16(a0, qf[0], z, 0, 0, 0);
      accS[tj] = __builtin_amdgcn_mfma_f32_16x16x32_bf16(a1, qf[1], z, 0, 0, 0);
    }

    // online softmax for this lane's q (=lr); kv spread over regs + lane bits 4,5
    float mx = accS[0][0];
#pragma unroll
    for (int tj = 0; tj < 8; ++tj)
#pragma unroll
      for (int r = 0; r < 4; ++r) mx = fmaxf(mx, accS[tj][r]);
    mx = fmaxf(mx, __shfl_xor(mx, 16));
    mx = fmaxf(mx, __shfl_xor(mx, 32));
    float mn = fmaxf(mrow, mx);
    float alpha = __expf(mrow - mn);
    float ps = 0.f;
#pragma unroll
    for (int tj = 0; tj < 8; ++tj)
#pragma unroll
      for (int r = 0; r < 4; ++r) {
        float p = __expf(accS[tj][r] - mn);
        accS[tj][r] = p;
        ps += p;
      }
    ps += __shfl_xor(ps, 16);
    ps += __shfl_xor(ps, 32);
    lrow = lrow * alpha + ps;
    mrow = mn;
#pragma unroll
    for (int t = 0; t < 4; ++t) accO[t] *= alpha;

    // O^T += V^T P^T : P^T B-frag (16x16x16) = packed accS of the SAME lane
#pragma unroll
    for (int st = 0; st < 8; ++st) {
      bf16x4 bfrag;
#pragma unroll
      for (int r = 0; r < 4; ++r) bfrag[r] = f2bf(accS[st][r]);
#pragma unroll
      for (int tjd = 0; tjd < 4; ++tjd) {
        bf16x4 afrag = *(const bf16x4*)&Vt[tjd * 16 + lr][st * 16 + lk * 4];
        accO[tjd] = __builtin_amdgcn_mfma_f32_16x16x16bf16_1k(afrag, bfrag, accO[tjd], 0, 0, 0);
      }
    }
  }

  // epilogue: O^T lane holds q=lr, d=tjd*16+lk*4+r -> 4 consecutive d per store (b64)
  const int b = bh >> 4, h = bh & 15;
  float inv = 1.f / lrow;
  size_t rowbase = (size_t)(b * SEQL + qw + lr) * DM + h * HS;
#pragma unroll
  for (int tjd = 0; tjd < 4; ++tjd) {
    bf16x4 o;
#pragma unroll
    for (int r = 0; r < 4; ++r) o[r] = f2bf(accO[tjd][r] * inv);
    *(bf16x4*)&Og[rowbase + tjd * 16 + lk * 4] = o;
  }
}

extern "C" void kernel_launch(void* const* d_in, const int* in_sizes, int n_in,
                              void* d_out, int out_size, void* d_ws, size_t ws_size,
                              hipStream_t stream) {
  const float* query  = (const float*)d_in[0];
  const float* key_in = (const float*)d_in[1];
  const float* value  = (const float*)d_in[2];
  const float* Wq = (const float*)d_in[3];
  const float* Wk = (const float*)d_in[4];
  const float* Wv = (const float*)d_in[5];
  const float* bq = (const float*)d_in[6];
  const float* bk = (const float*)d_in[7];
  const float* bv = (const float*)d_in[8];
  const float* Wo = (const float*)d_in[9];
  const float* bo = (const float*)d_in[10];
  float* out = (float*)d_out;          // FP32 output

  // ws layout (shorts), 32 MB total:
  //   [0,4M) Qb [b][h][s][64]; [4M,8M) Kb; [8M,12M) Vbt [b][h][64][s];
  //   [12M,16M) X: WtQ/WtK/WtV (QKV-GEMM phase) then At [4096][1024] (attn phase)
  short* ws  = (short*)d_ws;
  short* Qb  = ws;
  short* Kb  = Qb + (4 << 20);
  short* Vbt = Kb + (4 << 20);
  short* X   = Vbt + (4 << 20);
  short* WtQ = X;
  short* WtK = WtQ + (1 << 20);
  short* WtV = WtK + (1 << 20);
  short* At  = X;

  pack_w_kernel<<<dim3(16, 16, 3), 256, 0, stream>>>(Wq, Wk, Wv, WtQ, WtK, WtV);

  GemmArgs gq{query, WtQ, bq, Qb, nullptr, 0}, gk{key_in, WtK, bk, Kb, nullptr, 0},
           gv{value, WtV, bv, Vbt, nullptr, 2};
  gemm_bt_kernel<true, false><<<dim3(32, 8, 3), 256, 0, stream>>>(gq, gk, gv);

  attn_kernel<<<dim3(32, 32), 256, 0, stream>>>(Qb, Kb, Vbt, At);

  GemmArgs go{At, Wo, bo, nullptr, out, 1};
  gemm_bt_kernel<false, true><<<dim3(32, 8, 1), 256, 0, stream>>>(go, go, go);
}